// Round 1
// baseline (15.923 us; speedup 1.0000x reference)
//
#include <hip/hip_runtime.h>
#include <hip/hip_bf16.h>

// Problem constants (from reference setup_inputs)
#define XW   65536   // W
#define XC   256     // C
#define XL   512     // LATENT_DIM (output bins)
#define BIN  128     // W / L elements per bin

// One block per output bin l. 256 threads = 4 c-groups x 64 lanes.
// Each lane handles 2 consecutive w's (float2 load, 8B/lane coalesced).
// Only batch 0 of x is ever read (output depends only on batch 0).
__global__ __launch_bounds__(256) void statspool_kernel(
    const float* __restrict__ x,     // [B,C,1,W] -- we read only b=0
    const float* __restrict__ cw,    // [1,C]
    const float* __restrict__ cb,    // [1]
    const float* __restrict__ eps,   // [L]
    float* __restrict__ out)         // [1,L]
{
    const int l  = blockIdx.x;       // bin index 0..511
    const int t  = threadIdx.x;      // 0..255
    const int wi = t & 63;           // lane within wave -> 2 w's
    const int cg = t >> 6;           // c-group 0..3 (64 channels each)

    const int w0 = l * BIN + (wi << 1);
    const float* xp = x + (size_t)cg * 64 * XW + w0;

    float a0 = 0.f, a1 = 0.f;
    #pragma unroll 8
    for (int c = 0; c < 64; ++c) {
        const float wc = cw[(cg << 6) + c];            // wave-uniform -> s_load
        const float2 v = *(const float2*)(xp + (size_t)c * XW);
        a0 = fmaf(wc, v.x, a0);
        a1 = fmaf(wc, v.y, a1);
    }

    // Combine the 4 c-group partials per w via LDS (stride-1, conflict-free)
    __shared__ float part0[4][64];
    __shared__ float part1[4][64];
    part0[cg][wi] = a0;
    part1[cg][wi] = a1;
    __syncthreads();

    if (t < 64) {
        const float b  = cb[0];
        const float o0 = part0[0][wi] + part0[1][wi] + part0[2][wi] + part0[3][wi] + b;
        const float o1 = part1[0][wi] + part1[1][wi] + part1[2][wi] + part1[3][wi] + b;
        float s  = o0 + o1;            // partial sum over this lane's 2 w's
        float sq = fmaf(o0, o0, o1 * o1);

        // 64-lane wave reduction
        #pragma unroll
        for (int off = 32; off; off >>= 1) {
            s  += __shfl_down(s,  off);
            sq += __shfl_down(sq, off);
        }

        if (wi == 0) {
            const float inv  = 1.0f / (float)BIN;
            const float mean = s * inv;
            const float msq  = sq * inv;
            const float var  = fmaxf(msq - mean * mean, 0.0f);
            out[l] = fmaf(sqrtf(var), eps[l], mean);
        }
    }
}

extern "C" void kernel_launch(void* const* d_in, const int* in_sizes, int n_in,
                              void* d_out, int out_size, void* d_ws, size_t ws_size,
                              hipStream_t stream) {
    const float* x   = (const float*)d_in[0];   // [8,256,1,65536] f32
    const float* cw  = (const float*)d_in[1];   // [1,256] f32
    const float* cb  = (const float*)d_in[2];   // [1] f32
    const float* eps = (const float*)d_in[3];   // [512] f32
    float* out = (float*)d_out;                 // [1,512] f32

    statspool_kernel<<<dim3(XL), dim3(256), 0, stream>>>(x, cw, cb, eps, out);
}